// Round 1
// baseline (422.372 us; speedup 1.0000x reference)
//
#include <hip/hip_runtime.h>

#define BATCH 32768
#define HID 256
#define ACT 32

__global__ __launch_bounds__(256, 4) void nnue_fwd_kernel(
    const int* __restrict__ widx, const int* __restrict__ bidx,
    const float* __restrict__ stm,
    const float* __restrict__ ft_w, const float* __restrict__ ft_b,
    const float* __restrict__ l1_w, const float* __restrict__ l1_b,
    const float* __restrict__ l2_w, const float* __restrict__ l2_b,
    const float* __restrict__ l3_w, const float* __restrict__ l3_b,
    float* __restrict__ out)
{
    const int b = blockIdx.x;
    const int t = threadIdx.x;

    __shared__ int   sidx[64];     // 32 white + 32 black indices
    __shared__ float acc[2 * HID]; // stm-ordered concat accumulator
    __shared__ float x1[32];
    __shared__ float x2[32];

    // Stage the 64 indices once, coalesced.
    if (t < 32)       sidx[t]      = widx[b * ACT + t];
    else if (t < 64)  sidx[t]      = bidx[b * ACT + (t - 32)];
    __syncthreads();

    // Feature transform: thread t owns hidden channel t for both sides.
    float aw = ft_b[t];
    float ab = aw;
    #pragma unroll
    for (int k = 0; k < ACT; ++k) {
        aw += ft_w[(size_t)sidx[k] * HID + t];
    }
    #pragma unroll
    for (int k = 0; k < ACT; ++k) {
        ab += ft_w[(size_t)sidx[ACT + k] * HID + t];
    }
    aw = fminf(fmaxf(aw, 0.0f), 1.0f);
    ab = fminf(fmaxf(ab, 0.0f), 1.0f);

    // stm==1 -> [w, b]; stm==0 -> [b, w]
    const bool s = (stm[b] != 0.0f);
    acc[s ? t : t + HID] = aw;
    acc[s ? t + HID : t] = ab;
    __syncthreads();

    // L1: 32 outputs x (512 dot). 8 threads per output.
    {
        const int o     = t >> 3;  // 0..31
        const int lane8 = t & 7;
        const float* wrow = l1_w + o * 512;
        float p = 0.0f;
        #pragma unroll
        for (int j = 0; j < 512 / 8; ++j) {
            const int idx = lane8 + j * 8;
            p += acc[idx] * wrow[idx];
        }
        p += __shfl_down(p, 4, 8);
        p += __shfl_down(p, 2, 8);
        p += __shfl_down(p, 1, 8);
        if (lane8 == 0) x1[o] = fminf(fmaxf(p + l1_b[o], 0.0f), 1.0f);
    }
    __syncthreads();

    // L2: 32 outputs x (32 dot), one thread each.
    if (t < 32) {
        const float* wrow = l2_w + t * 32;
        float p = l2_b[t];
        #pragma unroll
        for (int j = 0; j < 32; ++j) p += x1[j] * wrow[j];
        x2[t] = fminf(fmaxf(p, 0.0f), 1.0f);
    }
    __syncthreads();

    // L3: single output.
    if (t == 0) {
        float p = l3_b[0];
        #pragma unroll
        for (int j = 0; j < 32; ++j) p += x2[j] * l3_w[j];
        out[b] = p;
    }
}

extern "C" void kernel_launch(void* const* d_in, const int* in_sizes, int n_in,
                              void* d_out, int out_size, void* d_ws, size_t ws_size,
                              hipStream_t stream) {
    const int*   widx = (const int*)d_in[0];
    const int*   bidx = (const int*)d_in[1];
    const float* stm  = (const float*)d_in[2];
    const float* ft_w = (const float*)d_in[3];
    const float* ft_b = (const float*)d_in[4];
    const float* l1_w = (const float*)d_in[5];
    const float* l1_b = (const float*)d_in[6];
    const float* l2_w = (const float*)d_in[7];
    const float* l2_b = (const float*)d_in[8];
    const float* l3_w = (const float*)d_in[9];
    const float* l3_b = (const float*)d_in[10];
    float* out = (float*)d_out;

    nnue_fwd_kernel<<<BATCH, 256, 0, stream>>>(
        widx, bidx, stm, ft_w, ft_b, l1_w, l1_b, l2_w, l2_b, l3_w, l3_b, out);
}

// Round 2
// 272.023 us; speedup vs baseline: 1.5527x; 1.5527x over previous
//
#include <hip/hip_runtime.h>

#define BATCH 32768
#define HID 256
#define ACT 32
#define G 4  // positions per block (one per wave)

__device__ __forceinline__ float4 clip4(float4 v) {
    v.x = fminf(fmaxf(v.x, 0.0f), 1.0f);
    v.y = fminf(fmaxf(v.y, 0.0f), 1.0f);
    v.z = fminf(fmaxf(v.z, 0.0f), 1.0f);
    v.w = fminf(fmaxf(v.w, 0.0f), 1.0f);
    return v;
}

__global__ __launch_bounds__(256, 6) void nnue_fwd_kernel(
    const int* __restrict__ widx, const int* __restrict__ bidx,
    const float* __restrict__ stm,
    const float* __restrict__ ft_w, const float* __restrict__ ft_b,
    const float* __restrict__ l1_w, const float* __restrict__ l1_b,
    const float* __restrict__ l2_w, const float* __restrict__ l2_b,
    const float* __restrict__ l3_w, const float* __restrict__ l3_b,
    float* __restrict__ out)
{
    const int bb = blockIdx.x;   // handles positions bb*G .. bb*G+3
    const int t  = threadIdx.x;
    const int w  = t >> 6;       // wave id == position slot
    const int q  = t & 63;       // float4 channel group (channels 4q..4q+3)

    __shared__ int    sidx[G * 64];       // per position: 32 white + 32 black
    __shared__ float4 accbuf[G][128];     // stm-ordered 512-wide concat, 8 KB
    __shared__ float  x1s[G][32];
    __shared__ float  x2s[G][32];

    // ---- stage indices (coalesced) ----
    {
        const int g = t >> 6, r = t & 63;
        int v;
        if (r < 32) v = widx[(bb * G + g) * ACT + r];
        else        v = bidx[(bb * G + g) * ACT + (r - 32)];
        sidx[t] = v;
    }
    __syncthreads();

    // ---- feature-transform gather: wave w owns position bb*G+w ----
    const float4* __restrict__ ftw4 = (const float4*)ft_w;
    const float4  bias = ((const float4*)ft_b)[q];
    float4 accW = bias, accB = bias;

    #pragma unroll
    for (int r = 0; r < 32; ++r) {
        const size_t row = (size_t)sidx[w * 64 + r];
        const float4 v = ftw4[row * 64 + q];
        accW.x += v.x; accW.y += v.y; accW.z += v.z; accW.w += v.w;
    }
    #pragma unroll
    for (int r = 0; r < 32; ++r) {
        const size_t row = (size_t)sidx[w * 64 + 32 + r];
        const float4 v = ftw4[row * 64 + q];
        accB.x += v.x; accB.y += v.y; accB.z += v.z; accB.w += v.w;
    }

    // stm==1 -> [w,b] ; stm==0 -> [b,w]
    const bool s = (stm[bb * G + w] != 0.0f);
    accbuf[w][(s ? 0 : 64) + q] = clip4(accW);
    accbuf[w][(s ? 64 : 0) + q] = clip4(accB);
    __syncthreads();

    // ---- L1: 32 outputs x 512-dot, 8 threads/output, all G positions ----
    {
        const int o  = t >> 3;   // 0..31
        const int l8 = t & 7;
        const float4* __restrict__ wrow = (const float4*)(l1_w + o * 512);
        float p0 = 0.f, p1 = 0.f, p2 = 0.f, p3 = 0.f;
        #pragma unroll
        for (int j = 0; j < 16; ++j) {
            const int i4 = l8 + j * 8;
            const float4 wv = wrow[i4];
            const float4 a0 = accbuf[0][i4];
            const float4 a1 = accbuf[1][i4];
            const float4 a2 = accbuf[2][i4];
            const float4 a3 = accbuf[3][i4];
            p0 += wv.x * a0.x + wv.y * a0.y + wv.z * a0.z + wv.w * a0.w;
            p1 += wv.x * a1.x + wv.y * a1.y + wv.z * a1.z + wv.w * a1.w;
            p2 += wv.x * a2.x + wv.y * a2.y + wv.z * a2.z + wv.w * a2.w;
            p3 += wv.x * a3.x + wv.y * a3.y + wv.z * a3.z + wv.w * a3.w;
        }
        p0 += __shfl_down(p0, 4, 8); p0 += __shfl_down(p0, 2, 8); p0 += __shfl_down(p0, 1, 8);
        p1 += __shfl_down(p1, 4, 8); p1 += __shfl_down(p1, 2, 8); p1 += __shfl_down(p1, 1, 8);
        p2 += __shfl_down(p2, 4, 8); p2 += __shfl_down(p2, 2, 8); p2 += __shfl_down(p2, 1, 8);
        p3 += __shfl_down(p3, 4, 8); p3 += __shfl_down(p3, 2, 8); p3 += __shfl_down(p3, 1, 8);
        if (l8 == 0) {
            const float bo = l1_b[o];
            x1s[0][o] = fminf(fmaxf(p0 + bo, 0.0f), 1.0f);
            x1s[1][o] = fminf(fmaxf(p1 + bo, 0.0f), 1.0f);
            x1s[2][o] = fminf(fmaxf(p2 + bo, 0.0f), 1.0f);
            x1s[3][o] = fminf(fmaxf(p3 + bo, 0.0f), 1.0f);
        }
    }
    __syncthreads();

    // ---- L2: 32x32 per position, 128 threads (one per (g, out)) ----
    if (t < G * 32) {
        const int g  = t >> 5;
        const int oo = t & 31;
        const float* __restrict__ wr = l2_w + oo * 32;
        float p = l2_b[oo];
        #pragma unroll
        for (int j = 0; j < 32; ++j) p += x1s[g][j] * wr[j];
        x2s[g][oo] = fminf(fmaxf(p, 0.0f), 1.0f);
    }
    __syncthreads();

    // ---- L3: one thread per position ----
    if (t < G) {
        float p = l3_b[0];
        #pragma unroll
        for (int j = 0; j < 32; ++j) p += x2s[t][j] * l3_w[j];
        out[bb * G + t] = p;
    }
}

extern "C" void kernel_launch(void* const* d_in, const int* in_sizes, int n_in,
                              void* d_out, int out_size, void* d_ws, size_t ws_size,
                              hipStream_t stream) {
    const int*   widx = (const int*)d_in[0];
    const int*   bidx = (const int*)d_in[1];
    const float* stm  = (const float*)d_in[2];
    const float* ft_w = (const float*)d_in[3];
    const float* ft_b = (const float*)d_in[4];
    const float* l1_w = (const float*)d_in[5];
    const float* l1_b = (const float*)d_in[6];
    const float* l2_w = (const float*)d_in[7];
    const float* l2_b = (const float*)d_in[8];
    const float* l3_w = (const float*)d_in[9];
    const float* l3_b = (const float*)d_in[10];
    float* out = (float*)d_out;

    nnue_fwd_kernel<<<BATCH / G, 256, 0, stream>>>(
        widx, bidx, stm, ft_w, ft_b, l1_w, l1_b, l2_w, l2_b, l3_w, l3_b, out);
}

// Round 3
// 265.791 us; speedup vs baseline: 1.5891x; 1.0234x over previous
//
#include <hip/hip_runtime.h>

#define BATCH 32768
#define HID 256
#define ACT 32
#define G 4  // positions per block (one per wave)

__device__ __forceinline__ float4 clip4(float4 v) {
    v.x = fminf(fmaxf(v.x, 0.0f), 1.0f);
    v.y = fminf(fmaxf(v.y, 0.0f), 1.0f);
    v.z = fminf(fmaxf(v.z, 0.0f), 1.0f);
    v.w = fminf(fmaxf(v.w, 0.0f), 1.0f);
    return v;
}

__device__ __forceinline__ void acc4(float4& a, const float4 v) {
    a.x += v.x; a.y += v.y; a.z += v.z; a.w += v.w;
}

__global__ __launch_bounds__(256, 4) void nnue_fwd_kernel(
    const int* __restrict__ widx, const int* __restrict__ bidx,
    const float* __restrict__ stm,
    const float* __restrict__ ft_w, const float* __restrict__ ft_b,
    const float* __restrict__ l1_w, const float* __restrict__ l1_b,
    const float* __restrict__ l2_w, const float* __restrict__ l2_b,
    const float* __restrict__ l3_w, const float* __restrict__ l3_b,
    float* __restrict__ out)
{
    const int bb = blockIdx.x;   // positions bb*G .. bb*G+3
    const int t  = threadIdx.x;
    const int w  = t >> 6;       // wave id == position slot
    const int q  = t & 63;       // float4 channel group (channels 4q..4q+3)

    __shared__ float4 accbuf[G][128];     // stm-ordered 512-wide concat, 8 KB
    __shared__ float  x1s[G][32];
    __shared__ float  x2s[G][32];

    const int pos = bb * G + w;

    // Lane q of wave w holds index q of its position (0..31 white, 32..63 black).
    int myidx;
    if (q < 32) myidx = widx[pos * ACT + q];
    else        myidx = bidx[pos * ACT + (q - 32)];

    // ---- feature-transform gather: wave-uniform rows via readlane -> SGPR ----
    const float4* __restrict__ ftw4 = (const float4*)ft_w;
    const float4  bias = ((const float4*)ft_b)[q];
    float4 accW = bias, accB = bias;

    #pragma unroll
    for (int r0 = 0; r0 < 32; r0 += 8) {
        float4 vw[8], vb[8];
        #pragma unroll
        for (int i = 0; i < 8; ++i) {
            const int rw = __builtin_amdgcn_readlane(myidx, r0 + i);
            vw[i] = ftw4[(size_t)rw * 64 + q];
        }
        #pragma unroll
        for (int i = 0; i < 8; ++i) {
            const int rb = __builtin_amdgcn_readlane(myidx, 32 + r0 + i);
            vb[i] = ftw4[(size_t)rb * 64 + q];
        }
        #pragma unroll
        for (int i = 0; i < 8; ++i) { acc4(accW, vw[i]); acc4(accB, vb[i]); }
    }

    // stm==1 -> [w,b] ; stm==0 -> [b,w]
    const bool s = (stm[pos] != 0.0f);
    accbuf[w][(s ? 0 : 64) + q] = clip4(accW);
    accbuf[w][(s ? 64 : 0) + q] = clip4(accB);
    __syncthreads();

    // ---- L1: 32 outputs x 512-dot, 8 threads/output, all G positions ----
    {
        const int o  = t >> 3;   // 0..31
        const int l8 = t & 7;
        const float4* __restrict__ wrow = (const float4*)(l1_w + o * 512);
        float p0 = 0.f, p1 = 0.f, p2 = 0.f, p3 = 0.f;
        #pragma unroll
        for (int j = 0; j < 16; ++j) {
            const int i4 = l8 + j * 8;
            const float4 wv = wrow[i4];
            const float4 a0 = accbuf[0][i4];
            const float4 a1 = accbuf[1][i4];
            const float4 a2 = accbuf[2][i4];
            const float4 a3 = accbuf[3][i4];
            p0 += wv.x * a0.x + wv.y * a0.y + wv.z * a0.z + wv.w * a0.w;
            p1 += wv.x * a1.x + wv.y * a1.y + wv.z * a1.z + wv.w * a1.w;
            p2 += wv.x * a2.x + wv.y * a2.y + wv.z * a2.z + wv.w * a2.w;
            p3 += wv.x * a3.x + wv.y * a3.y + wv.z * a3.z + wv.w * a3.w;
        }
        p0 += __shfl_down(p0, 4, 8); p0 += __shfl_down(p0, 2, 8); p0 += __shfl_down(p0, 1, 8);
        p1 += __shfl_down(p1, 4, 8); p1 += __shfl_down(p1, 2, 8); p1 += __shfl_down(p1, 1, 8);
        p2 += __shfl_down(p2, 4, 8); p2 += __shfl_down(p2, 2, 8); p2 += __shfl_down(p2, 1, 8);
        p3 += __shfl_down(p3, 4, 8); p3 += __shfl_down(p3, 2, 8); p3 += __shfl_down(p3, 1, 8);
        if (l8 == 0) {
            const float bo = l1_b[o];
            x1s[0][o] = fminf(fmaxf(p0 + bo, 0.0f), 1.0f);
            x1s[1][o] = fminf(fmaxf(p1 + bo, 0.0f), 1.0f);
            x1s[2][o] = fminf(fmaxf(p2 + bo, 0.0f), 1.0f);
            x1s[3][o] = fminf(fmaxf(p3 + bo, 0.0f), 1.0f);
        }
    }
    __syncthreads();

    // ---- L2: 32x32 per position, 128 threads (one per (g, out)) ----
    if (t < G * 32) {
        const int g  = t >> 5;
        const int oo = t & 31;
        const float* __restrict__ wr = l2_w + oo * 32;
        float p = l2_b[oo];
        #pragma unroll
        for (int j = 0; j < 32; ++j) p += x1s[g][j] * wr[j];
        x2s[g][oo] = fminf(fmaxf(p, 0.0f), 1.0f);
    }
    __syncthreads();

    // ---- L3: one thread per position ----
    if (t < G) {
        float p = l3_b[0];
        #pragma unroll
        for (int j = 0; j < 32; ++j) p += x2s[t][j] * l3_w[j];
        out[bb * G + t] = p;
    }
}

extern "C" void kernel_launch(void* const* d_in, const int* in_sizes, int n_in,
                              void* d_out, int out_size, void* d_ws, size_t ws_size,
                              hipStream_t stream) {
    const int*   widx = (const int*)d_in[0];
    const int*   bidx = (const int*)d_in[1];
    const float* stm  = (const float*)d_in[2];
    const float* ft_w = (const float*)d_in[3];
    const float* ft_b = (const float*)d_in[4];
    const float* l1_w = (const float*)d_in[5];
    const float* l1_b = (const float*)d_in[6];
    const float* l2_w = (const float*)d_in[7];
    const float* l2_b = (const float*)d_in[8];
    const float* l3_w = (const float*)d_in[9];
    const float* l3_b = (const float*)d_in[10];
    float* out = (float*)d_out;

    nnue_fwd_kernel<<<BATCH / G, 256, 0, stream>>>(
        widx, bidx, stm, ft_w, ft_b, l1_w, l1_b, l2_w, l2_b, l3_w, l3_b, out);
}

// Round 4
// 136.574 us; speedup vs baseline: 3.0926x; 1.9461x over previous
//
#include <hip/hip_runtime.h>

#define BATCH 32768
#define HID 256
#define ACT 32
#define NROWS 40960

#define TBL_BYTES ((size_t)NROWS * HID * 2)       // 20,971,520 (bf16, group-major)
#define ACT_BYTES ((size_t)BATCH * 512 * 4)       // 67,108,864 (fp32 activations)

// ============ kernel 0: fp32 [40960][256] -> bf16 group-major [8][40960][32] ============
__global__ __launch_bounds__(256) void nnue_cvt_kernel(
    const float* __restrict__ ft_w, unsigned short* __restrict__ tbl)
{
    const int g  = blockIdx.y;
    const int tx = blockIdx.x * 256 + threadIdx.x;   // 0 .. 40960*4-1
    const int row = tx >> 2;
    const int c8  = tx & 3;                          // 8-channel chunk within group
    const float* __restrict__ src = ft_w + (size_t)row * HID + g * 32 + c8 * 8;
    unsigned int o[8];
    #pragma unroll
    for (int j = 0; j < 8; ++j) {
        unsigned int u = __float_as_uint(src[j]);
        u = u + 0x7FFFu + ((u >> 16) & 1u);          // round-to-nearest-even bf16
        o[j] = u >> 16;
    }
    uint4 pack;
    pack.x = o[0] | (o[1] << 16);
    pack.y = o[2] | (o[3] << 16);
    pack.z = o[4] | (o[5] << 16);
    pack.w = o[6] | (o[7] << 16);
    *(uint4*)(tbl + ((size_t)g * NROWS + row) * 32 + c8 * 8) = pack;
}

// ============ kernel 1: FT gather (one 32-channel group per block, 16 positions) ============
__global__ __launch_bounds__(256, 4) void nnue_ft_kernel(
    const int* __restrict__ widx, const int* __restrict__ bidx,
    const float* __restrict__ stm,
    const unsigned short* __restrict__ tbl, const float* __restrict__ ft_b,
    float* __restrict__ act)
{
    const int bid = blockIdx.x;
    const int g   = bid & 7;          // column group -> XCD (round-robin dispatch)
    const int pt  = bid >> 3;         // position tile (16 positions)
    const int t   = threadIdx.x;
    const int w   = t >> 6;           // wave id
    const int q   = t & 63;
    const int r   = q >> 3;           // 0..7 : row slot within a gather instruction
    const int c   = q & 7;            // 0..7 : 4-channel chunk within group

    __shared__ int   sidx[16][64];
    __shared__ float sstm[16];

    // stage 16 positions x 64 indices, coalesced
    #pragma unroll
    for (int k = 0; k < 2; ++k) {
        const int u = t + k * 256;            // 0..511
        const int p = u >> 5, rr = u & 31;
        sidx[p][rr]      = widx[(size_t)(pt * 16 + p) * ACT + rr];
        sidx[p][32 + rr] = bidx[(size_t)(pt * 16 + p) * ACT + rr];
    }
    if (t < 16) sstm[t] = stm[pt * 16 + t];
    __syncthreads();

    const unsigned short* __restrict__ tg = tbl + (size_t)g * NROWS * 32;
    const float4 bv = ((const float4*)ft_b)[g * 8 + c];   // channels g*32 + c*4 ..+3

    for (int i = 0; i < 4; ++i) {
        const int p   = w * 4 + i;
        const int pos = pt * 16 + p;

        // 8 gather instructions: k<4 white rows, k>=4 black rows (8 rows each)
        uint2 raw[8];
        #pragma unroll
        for (int k = 0; k < 8; ++k) {
            const int rowid = sidx[p][k * 8 + r];
            raw[k] = *(const uint2*)(tg + ((size_t)rowid << 5) + (c << 2));
        }

        float a0=0.f,a1=0.f,a2=0.f,a3=0.f;
        float b0=0.f,b1=0.f,b2=0.f,b3=0.f;
        #pragma unroll
        for (int k = 0; k < 4; ++k) {
            a0 += __uint_as_float(raw[k].x << 16);
            a1 += __uint_as_float(raw[k].x & 0xFFFF0000u);
            a2 += __uint_as_float(raw[k].y << 16);
            a3 += __uint_as_float(raw[k].y & 0xFFFF0000u);
        }
        #pragma unroll
        for (int k = 4; k < 8; ++k) {
            b0 += __uint_as_float(raw[k].x << 16);
            b1 += __uint_as_float(raw[k].x & 0xFFFF0000u);
            b2 += __uint_as_float(raw[k].y << 16);
            b3 += __uint_as_float(raw[k].y & 0xFFFF0000u);
        }

        // reduce over r (lane bits 3..5) -> every lane holds full 32-row sums
        #pragma unroll
        for (int m = 8; m < 64; m <<= 1) {
            a0 += __shfl_xor(a0, m, 64);
            a1 += __shfl_xor(a1, m, 64);
            a2 += __shfl_xor(a2, m, 64);
            a3 += __shfl_xor(a3, m, 64);
            b0 += __shfl_xor(b0, m, 64);
            b1 += __shfl_xor(b1, m, 64);
            b2 += __shfl_xor(b2, m, 64);
            b3 += __shfl_xor(b3, m, 64);
        }

        const float w0 = fminf(fmaxf(a0 + bv.x, 0.f), 1.f);
        const float w1 = fminf(fmaxf(a1 + bv.y, 0.f), 1.f);
        const float w2 = fminf(fmaxf(a2 + bv.z, 0.f), 1.f);
        const float w3 = fminf(fmaxf(a3 + bv.w, 0.f), 1.f);
        const float z0 = fminf(fmaxf(b0 + bv.x, 0.f), 1.f);
        const float z1 = fminf(fmaxf(b1 + bv.y, 0.f), 1.f);
        const float z2 = fminf(fmaxf(b2 + bv.z, 0.f), 1.f);
        const float z3 = fminf(fmaxf(b3 + bv.w, 0.f), 1.f);

        if (r == 0) {
            const bool s = (sstm[p] != 0.0f);
            float* dst = act + (size_t)pos * 512 + g * 32 + (c << 2);
            float4 wa; wa.x=w0; wa.y=w1; wa.z=w2; wa.w=w3;
            float4 za; za.x=z0; za.y=z1; za.z=z2; za.w=z3;
            *(float4*)(dst + (s ? 0 : 256)) = wa;
            *(float4*)(dst + (s ? 256 : 0)) = za;
        }
    }
}

// ============ kernel 2: MLP (8 positions per block) ============
__global__ __launch_bounds__(256, 4) void nnue_mlp_kernel(
    const float* __restrict__ act,
    const float* __restrict__ l1_w, const float* __restrict__ l1_b,
    const float* __restrict__ l2_w, const float* __restrict__ l2_b,
    const float* __restrict__ l3_w, const float* __restrict__ l3_b,
    float* __restrict__ out)
{
    const int bb = blockIdx.x;       // positions bb*8 .. bb*8+7
    const int t  = threadIdx.x;

    __shared__ float4 sact[8 * 128]; // 8 positions x 512 fp32 = 16 KB
    __shared__ float  x1s[8][32];
    __shared__ float  x2s[8][32];

    const float4* __restrict__ ga = (const float4*)(act + (size_t)bb * 8 * 512);
    #pragma unroll
    for (int k = 0; k < 4; ++k) sact[t + k * 256] = ga[t + k * 256];
    __syncthreads();

    // L1: 32 outputs x 512-dot, 8 threads/output, 8 positions
    {
        const int o  = t >> 3;
        const int l8 = t & 7;
        const float4* __restrict__ wrow = (const float4*)(l1_w + o * 512);
        float pacc[8] = {0.f,0.f,0.f,0.f,0.f,0.f,0.f,0.f};
        #pragma unroll
        for (int j = 0; j < 16; ++j) {
            const int i4 = l8 + j * 8;
            const float4 wv = wrow[i4];
            #pragma unroll
            for (int p = 0; p < 8; ++p) {
                const float4 a = sact[p * 128 + i4];
                pacc[p] += wv.x*a.x + wv.y*a.y + wv.z*a.z + wv.w*a.w;
            }
        }
        #pragma unroll
        for (int p = 0; p < 8; ++p) {
            pacc[p] += __shfl_down(pacc[p], 4, 8);
            pacc[p] += __shfl_down(pacc[p], 2, 8);
            pacc[p] += __shfl_down(pacc[p], 1, 8);
        }
        if (l8 == 0) {
            const float bo = l1_b[o];
            #pragma unroll
            for (int p = 0; p < 8; ++p)
                x1s[p][o] = fminf(fmaxf(pacc[p] + bo, 0.f), 1.f);
        }
    }
    __syncthreads();

    // L2: 256 threads = 8 positions x 32 outputs
    {
        const int p  = t >> 5;
        const int oo = t & 31;
        const float* __restrict__ wr = l2_w + oo * 32;
        float s2 = l2_b[oo];
        #pragma unroll
        for (int j = 0; j < 32; ++j) s2 += x1s[p][j] * wr[j];
        x2s[p][oo] = fminf(fmaxf(s2, 0.f), 1.f);
    }
    __syncthreads();

    // L3
    if (t < 8) {
        float s3 = l3_b[0];
        #pragma unroll
        for (int j = 0; j < 32; ++j) s3 += x2s[t][j] * l3_w[j];
        out[bb * 8 + t] = s3;
    }
}

// ============ fallback (round-3 kernel) if ws_size is insufficient ============
__device__ __forceinline__ float4 clip4(float4 v) {
    v.x = fminf(fmaxf(v.x, 0.0f), 1.0f);
    v.y = fminf(fmaxf(v.y, 0.0f), 1.0f);
    v.z = fminf(fmaxf(v.z, 0.0f), 1.0f);
    v.w = fminf(fmaxf(v.w, 0.0f), 1.0f);
    return v;
}
__device__ __forceinline__ void acc4(float4& a, const float4 v) {
    a.x += v.x; a.y += v.y; a.z += v.z; a.w += v.w;
}

__global__ __launch_bounds__(256, 4) void nnue_fwd_fallback(
    const int* __restrict__ widx, const int* __restrict__ bidx,
    const float* __restrict__ stm,
    const float* __restrict__ ft_w, const float* __restrict__ ft_b,
    const float* __restrict__ l1_w, const float* __restrict__ l1_b,
    const float* __restrict__ l2_w, const float* __restrict__ l2_b,
    const float* __restrict__ l3_w, const float* __restrict__ l3_b,
    float* __restrict__ out)
{
    const int bb = blockIdx.x;
    const int t  = threadIdx.x;
    const int w  = t >> 6;
    const int q  = t & 63;

    __shared__ float4 accbuf[4][128];
    __shared__ float  x1s[4][32];
    __shared__ float  x2s[4][32];

    const int pos = bb * 4 + w;
    int myidx;
    if (q < 32) myidx = widx[pos * ACT + q];
    else        myidx = bidx[pos * ACT + (q - 32)];

    const float4* __restrict__ ftw4 = (const float4*)ft_w;
    const float4  bias = ((const float4*)ft_b)[q];
    float4 accW = bias, accB = bias;

    #pragma unroll
    for (int r0 = 0; r0 < 32; r0 += 8) {
        float4 vw[8], vb[8];
        #pragma unroll
        for (int i = 0; i < 8; ++i) {
            const int rw = __builtin_amdgcn_readlane(myidx, r0 + i);
            vw[i] = ftw4[(size_t)rw * 64 + q];
        }
        #pragma unroll
        for (int i = 0; i < 8; ++i) {
            const int rb = __builtin_amdgcn_readlane(myidx, 32 + r0 + i);
            vb[i] = ftw4[(size_t)rb * 64 + q];
        }
        #pragma unroll
        for (int i = 0; i < 8; ++i) { acc4(accW, vw[i]); acc4(accB, vb[i]); }
    }

    const bool s = (stm[pos] != 0.0f);
    accbuf[w][(s ? 0 : 64) + q] = clip4(accW);
    accbuf[w][(s ? 64 : 0) + q] = clip4(accB);
    __syncthreads();

    {
        const int o  = t >> 3;
        const int l8 = t & 7;
        const float4* __restrict__ wrow = (const float4*)(l1_w + o * 512);
        float p0 = 0.f, p1 = 0.f, p2 = 0.f, p3 = 0.f;
        #pragma unroll
        for (int j = 0; j < 16; ++j) {
            const int i4 = l8 + j * 8;
            const float4 wv = wrow[i4];
            const float4 a0 = accbuf[0][i4];
            const float4 a1 = accbuf[1][i4];
            const float4 a2 = accbuf[2][i4];
            const float4 a3 = accbuf[3][i4];
            p0 += wv.x*a0.x + wv.y*a0.y + wv.z*a0.z + wv.w*a0.w;
            p1 += wv.x*a1.x + wv.y*a1.y + wv.z*a1.z + wv.w*a1.w;
            p2 += wv.x*a2.x + wv.y*a2.y + wv.z*a2.z + wv.w*a2.w;
            p3 += wv.x*a3.x + wv.y*a3.y + wv.z*a3.z + wv.w*a3.w;
        }
        p0 += __shfl_down(p0, 4, 8); p0 += __shfl_down(p0, 2, 8); p0 += __shfl_down(p0, 1, 8);
        p1 += __shfl_down(p1, 4, 8); p1 += __shfl_down(p1, 2, 8); p1 += __shfl_down(p1, 1, 8);
        p2 += __shfl_down(p2, 4, 8); p2 += __shfl_down(p2, 2, 8); p2 += __shfl_down(p2, 1, 8);
        p3 += __shfl_down(p3, 4, 8); p3 += __shfl_down(p3, 2, 8); p3 += __shfl_down(p3, 1, 8);
        if (l8 == 0) {
            const float bo = l1_b[o];
            x1s[0][o] = fminf(fmaxf(p0 + bo, 0.0f), 1.0f);
            x1s[1][o] = fminf(fmaxf(p1 + bo, 0.0f), 1.0f);
            x1s[2][o] = fminf(fmaxf(p2 + bo, 0.0f), 1.0f);
            x1s[3][o] = fminf(fmaxf(p3 + bo, 0.0f), 1.0f);
        }
    }
    __syncthreads();

    if (t < 128) {
        const int g  = t >> 5;
        const int oo = t & 31;
        const float* __restrict__ wr = l2_w + oo * 32;
        float p = l2_b[oo];
        #pragma unroll
        for (int j = 0; j < 32; ++j) p += x1s[g][j] * wr[j];
        x2s[g][oo] = fminf(fmaxf(p, 0.0f), 1.0f);
    }
    __syncthreads();

    if (t < 4) {
        float p = l3_b[0];
        #pragma unroll
        for (int j = 0; j < 32; ++j) p += x2s[t][j] * l3_w[j];
        out[bb * 4 + t] = p;
    }
}

extern "C" void kernel_launch(void* const* d_in, const int* in_sizes, int n_in,
                              void* d_out, int out_size, void* d_ws, size_t ws_size,
                              hipStream_t stream) {
    const int*   widx = (const int*)d_in[0];
    const int*   bidx = (const int*)d_in[1];
    const float* stm  = (const float*)d_in[2];
    const float* ft_w = (const float*)d_in[3];
    const float* ft_b = (const float*)d_in[4];
    const float* l1_w = (const float*)d_in[5];
    const float* l1_b = (const float*)d_in[6];
    const float* l2_w = (const float*)d_in[7];
    const float* l2_b = (const float*)d_in[8];
    const float* l3_w = (const float*)d_in[9];
    const float* l3_b = (const float*)d_in[10];
    float* out = (float*)d_out;

    if (ws_size >= TBL_BYTES + ACT_BYTES) {
        unsigned short* tbl = (unsigned short*)d_ws;
        float* act = (float*)((char*)d_ws + TBL_BYTES);
        nnue_cvt_kernel<<<dim3(640, 8), 256, 0, stream>>>(ft_w, tbl);
        nnue_ft_kernel<<<(BATCH / 16) * 8, 256, 0, stream>>>(widx, bidx, stm, tbl, ft_b, act);
        nnue_mlp_kernel<<<BATCH / 8, 256, 0, stream>>>(act, l1_w, l1_b, l2_w, l2_b, l3_w, l3_b, out);
    } else {
        nnue_fwd_fallback<<<BATCH / 4, 256, 0, stream>>>(
            widx, bidx, stm, ft_w, ft_b, l1_w, l1_b, l2_w, l2_b, l3_w, l3_b, out);
    }
}